// Round 12
// baseline (525.785 us; speedup 1.0000x reference)
//
#include <hip/hip_runtime.h>
#include <hip/hip_cooperative_groups.h>

namespace cg = cooperative_groups;

// GCN layer: out = relu( G(feature) @ W^T + b ), G = mean over in-edges (or
// identity for isolated nodes).  N=50000, F=64, E=800000.
//
// GEMM commutes with the (linear) aggregation: G(feat) @ W^T == G(feat @ W^T).
// Round-12: dispatch-count collapse. Evidence: rounds 10/11 showed real-work
// reductions (bf16 Y halving gather traffic) move dur_us by ~2us while the
// total sits at ~108us -> ~6-8us per-dispatch launch/drain overhead x 8
// dispatches dominates. New structure: TWO dispatches:
//   1. k_gemm: Ybf = bf16(feature @ W^T)  (+ grid-stride zero of deg)
//   2. k_fused (cooperative): deg+rank -> part -> final(fused root scan) ->
//      bucket -> gather, separated by grid.sync().
// Fallback to the proven multi-kernel path if cooperative launch fails.

#define F 64
#define SCAN_BLK 256
#define SCAN_ELEMS 1024

typedef unsigned int uint;
typedef unsigned short ushort;

__device__ __forceinline__ ushort f2bf(float x) {
    uint u = __float_as_uint(x);
    u += 0x7FFFu + ((u >> 16) & 1u);   // round-to-nearest-even
    return (ushort)(u >> 16);
}

// ---------- K4: Ybf = bf16( feature @ W^T ), plus deg zeroing ----------
__global__ __launch_bounds__(256) void k_gemm(const float* __restrict__ feature,
                                              const float* __restrict__ W,
                                              ushort* __restrict__ Ybf, int N,
                                              int* __restrict__ deg, int n4) {
    // grid-stride zero of deg (runs before k_fused via kernel boundary)
    {
        int gt = blockIdx.x * 256 + threadIdx.x;
        for (int i = gt; i < n4; i += gridDim.x * 256)
            ((int4*)deg)[i] = make_int4(0, 0, 0, 0);
    }
    __shared__ float sWt[64 * 76];
    __shared__ float shh[32 * 72];
    int tid = threadIdx.x;
    for (int i = tid; i < 4096; i += 256) {
        int fo = i >> 6, k = i & 63;
        sWt[k * 76 + fo] = W[i];
    }
    int n0blk = blockIdx.x * 32;
    for (int i = tid; i < 512; i += 256) {        // 32 rows x 16 float4
        int r = i >> 4, c4 = i & 15;
        int n = n0blk + r;
        float4 v = make_float4(0.f, 0.f, 0.f, 0.f);
        if (n < N) v = ((const float4*)feature)[(long)n * 16 + c4];
        *(float4*)&shh[r * 72 + c4 * 4] = v;
    }
    __syncthreads();
    int npair = tid >> 4, foq = tid & 15;
    int r0 = npair * 2, r1 = r0 + 1;
    float a0=0,a1=0,a2=0,a3=0,b0=0,b1=0,b2=0,b3=0;
#pragma unroll 8
    for (int k = 0; k < 64; ++k) {
        float hA = shh[r0 * 72 + k];
        float hB = shh[r1 * 72 + k];
        float4 wv = *(const float4*)&sWt[k * 76 + foq * 4];
        a0 = fmaf(hA, wv.x, a0); a1 = fmaf(hA, wv.y, a1);
        a2 = fmaf(hA, wv.z, a2); a3 = fmaf(hA, wv.w, a3);
        b0 = fmaf(hB, wv.x, b0); b1 = fmaf(hB, wv.y, b1);
        b2 = fmaf(hB, wv.z, b2); b3 = fmaf(hB, wv.w, b3);
    }
    int nA = n0blk + r0, nB = n0blk + r1;
    if (nA < N) ((ushort4*)Ybf)[(long)nA * 16 + foq] =
        make_ushort4(f2bf(a0), f2bf(a1), f2bf(a2), f2bf(a3));
    if (nB < N) ((ushort4*)Ybf)[(long)nB * 16 + foq] =
        make_ushort4(f2bf(b0), f2bf(b1), f2bf(b2), f2bf(b3));
}

// ---------- fused cooperative kernel: deg -> scan -> bucket -> gather ------
__global__ __launch_bounds__(256, 4) void k_fused(
    const int* __restrict__ esrc, const int* __restrict__ edst,
    int* __restrict__ deg, int* __restrict__ rank,
    int* __restrict__ part, int* __restrict__ off, int* __restrict__ bucket,
    const ushort* __restrict__ Ybf, const float* __restrict__ bias,
    float* __restrict__ out, int N, int E, int nbChunks)
{
    cg::grid_group grid = cg::this_grid();
    int NB  = gridDim.x;
    int bid = blockIdx.x, tid = threadIdx.x;
    int gthreads = NB * 256;
    int gtid = bid * 256 + tid;

    // ---- phase 1: degree histogram + per-edge rank ----
    {
        int ng4 = (E + 3) >> 2;
        for (int i = gtid; i < ng4; i += gthreads) {
            int base = i * 4;
            if (base + 3 < E) {
                int4 d4 = *(const int4*)(edst + base);
                int r0 = atomicAdd(&deg[d4.x], 1);
                int r1 = atomicAdd(&deg[d4.y], 1);
                int r2 = atomicAdd(&deg[d4.z], 1);
                int r3 = atomicAdd(&deg[d4.w], 1);
                *(int4*)(rank + base) = make_int4(r0, r1, r2, r3);
            } else {
                for (int e = base; e < E; ++e)
                    rank[e] = atomicAdd(&deg[edst[e]], 1);
            }
        }
    }
    grid.sync();
    // ---- phase 2: per-chunk partial sums ----
    if (bid < nbChunks) {
        int i0 = bid * SCAN_ELEMS + tid * 4;
        int s = 0;
#pragma unroll
        for (int k = 0; k < 4; ++k) { int i = i0 + k; if (i < N) s += deg[i]; }
        for (int d = 32; d; d >>= 1) s += __shfl_down(s, d);
        __shared__ int red[4];
        int w = tid >> 6;
        if ((tid & 63) == 0) red[w] = s;
        __syncthreads();
        if (tid == 0) part[bid] = red[0] + red[1] + red[2] + red[3];
    }
    grid.sync();
    // ---- phase 3: chunk scan with fused root scan (nbChunks <= 64) ----
    if (bid < nbChunks) {
        __shared__ int s_base;
        if (tid < 64) {
            int v = (tid < nbChunks) ? part[tid] : 0;
            for (int d = 1; d < 64; d <<= 1) {
                int t = __shfl_up(v, d);
                if (tid >= d) v += t;
            }
            if (tid == bid) s_base = v - part[bid];   // exclusive base
        }
        int i0 = bid * SCAN_ELEMS + tid * 4;
        int v4[4]; int s = 0;
#pragma unroll
        for (int k = 0; k < 4; ++k) { int i = i0 + k; v4[k] = (i < N) ? deg[i] : 0; s += v4[k]; }
        __shared__ int sc[SCAN_BLK];
        sc[tid] = s;
        __syncthreads();
        for (int d = 1; d < SCAN_BLK; d <<= 1) {
            int t = (tid >= d) ? sc[tid - d] : 0;
            __syncthreads();
            sc[tid] += t;
            __syncthreads();
        }
        int run = s_base + sc[tid] - s;
#pragma unroll
        for (int k = 0; k < 4; ++k) {
            int i = i0 + k;
            if (i < N) { off[i] = run; run += v4[k]; }
        }
        if (bid == 0 && tid == 0) off[N] = E;
    }
    grid.sync();
    // ---- phase 4: atomic-free bucket scatter ----
    {
        int ng4 = (E + 3) >> 2;
        for (int i = gtid; i < ng4; i += gthreads) {
            int base = i * 4;
            if (base + 3 < E) {
                int4 d4 = *(const int4*)(edst + base);
                int4 r4 = *(const int4*)(rank + base);
                int4 s4 = *(const int4*)(esrc + base);
                bucket[off[d4.x] + r4.x] = s4.x;
                bucket[off[d4.y] + r4.y] = s4.y;
                bucket[off[d4.z] + r4.z] = s4.z;
                bucket[off[d4.w] + r4.w] = s4.w;
            } else {
                for (int e = base; e < E; ++e)
                    bucket[off[edst[e]] + rank[e]] = esrc[e];
            }
        }
    }
    grid.sync();
    // ---- phase 5: gather-mean over bf16 Y + bias + relu ----
    {
        int w = tid >> 6, lane = tid & 63;
        int g = lane >> 3, c = lane & 7;
        const uint4* Y16 = (const uint4*)Ybf;
        for (int n = bid * 4 + w; n < N; n += NB * 4) {
            int beg = off[n], end = off[n + 1];
            int d = end - beg;
            float acc[4][8];
#pragma unroll
            for (int ch = 0; ch < 4; ++ch)
#pragma unroll
                for (int j = 0; j < 8; ++j) acc[ch][j] = 0.f;
            int last = end - 1;
            for (int base = beg; base < end; base += 32) {
#pragma unroll
                for (int ch = 0; ch < 4; ++ch) {
                    int jdx = base + ch * 8 + g;
                    int s = bucket[min(jdx, last)];
                    uint4 q = Y16[(long)s * 8 + c];
                    if (jdx < end) {
                        acc[ch][0] += __uint_as_float(q.x << 16);
                        acc[ch][1] += __uint_as_float(q.x & 0xFFFF0000u);
                        acc[ch][2] += __uint_as_float(q.y << 16);
                        acc[ch][3] += __uint_as_float(q.y & 0xFFFF0000u);
                        acc[ch][4] += __uint_as_float(q.z << 16);
                        acc[ch][5] += __uint_as_float(q.z & 0xFFFF0000u);
                        acc[ch][6] += __uint_as_float(q.w << 16);
                        acc[ch][7] += __uint_as_float(q.w & 0xFFFF0000u);
                    }
                }
            }
#pragma unroll
            for (int j = 0; j < 8; ++j)
                acc[0][j] += (acc[1][j] + acc[2][j]) + acc[3][j];
#pragma unroll
            for (int j = 0; j < 8; ++j) {
                float v = acc[0][j];
                v += __shfl_xor(v, 8);
                v += __shfl_xor(v, 16);
                v += __shfl_xor(v, 32);
                acc[0][j] = v;
            }
            float sel = acc[0][0];
#pragma unroll
            for (int j = 1; j < 8; ++j) sel = (g == j) ? acc[0][j] : sel;
            int fw = c * 8 + g;
            float hv;
            if (d > 0) {
                hv = sel / (float)d;
            } else {
                hv = __uint_as_float(((uint)Ybf[(long)n * F + fw]) << 16);
            }
            out[(long)n * F + fw] = fmaxf(hv + bias[fw], 0.0f);
        }
    }
}

// ================= fallback multi-kernel path (round-11, proven) ===========
__global__ __launch_bounds__(256) void k_deg(const int* __restrict__ edst,
                                             int* __restrict__ deg,
                                             int* __restrict__ rank, int E) {
    int base = (blockIdx.x * 256 + threadIdx.x) * 4;
    if (base + 3 < E) {
        int4 d4 = *(const int4*)(edst + base);
        int r0 = atomicAdd(&deg[d4.x], 1);
        int r1 = atomicAdd(&deg[d4.y], 1);
        int r2 = atomicAdd(&deg[d4.z], 1);
        int r3 = atomicAdd(&deg[d4.w], 1);
        *(int4*)(rank + base) = make_int4(r0, r1, r2, r3);
    } else {
        for (int e = base; e < E; ++e)
            rank[e] = atomicAdd(&deg[edst[e]], 1);
    }
}

__global__ __launch_bounds__(SCAN_BLK) void k_part(const int* __restrict__ deg,
                                                   int* __restrict__ part, int N) {
    int b = blockIdx.x, tid = threadIdx.x;
    int i0 = b * SCAN_ELEMS + tid * 4;
    int s = 0;
#pragma unroll
    for (int k = 0; k < 4; ++k) { int i = i0 + k; if (i < N) s += deg[i]; }
    for (int d = 32; d; d >>= 1) s += __shfl_down(s, d);
    __shared__ int red[4];
    int w = tid >> 6;
    if ((tid & 63) == 0) red[w] = s;
    __syncthreads();
    if (tid == 0) part[b] = red[0] + red[1] + red[2] + red[3];
}

__global__ __launch_bounds__(SCAN_BLK) void k_final(const int* __restrict__ deg,
                                                    const int* __restrict__ part,
                                                    int* __restrict__ off,
                                                    int N, int E, int nb) {
    int b = blockIdx.x, tid = threadIdx.x;
    __shared__ int s_base;
    if (tid < 64) {
        int v = (tid < nb) ? part[tid] : 0;
        for (int d = 1; d < 64; d <<= 1) {
            int t = __shfl_up(v, d);
            if (tid >= d) v += t;
        }
        if (tid == b) s_base = v - ((b < nb) ? part[b] : 0);
    }
    int i0 = b * SCAN_ELEMS + tid * 4;
    int v[4]; int s = 0;
#pragma unroll
    for (int k = 0; k < 4; ++k) { int i = i0 + k; v[k] = (i < N) ? deg[i] : 0; s += v[k]; }
    __shared__ int sc[SCAN_BLK];
    sc[tid] = s;
    __syncthreads();
    for (int d = 1; d < SCAN_BLK; d <<= 1) {
        int t = (tid >= d) ? sc[tid - d] : 0;
        __syncthreads();
        sc[tid] += t;
        __syncthreads();
    }
    int exc = sc[tid] - s;
    int run = s_base + exc;
#pragma unroll
    for (int k = 0; k < 4; ++k) {
        int i = i0 + k;
        if (i < N) { off[i] = run; run += v[k]; }
    }
    if (b == 0 && tid == 0) off[N] = E;
}

__global__ __launch_bounds__(256) void k_bucket(const int* __restrict__ esrc,
                                                const int* __restrict__ edst,
                                                const int* __restrict__ off,
                                                const int* __restrict__ rank,
                                                int* __restrict__ bucket, int E) {
    int base = (blockIdx.x * 256 + threadIdx.x) * 4;
    if (base + 3 < E) {
        int4 d4 = *(const int4*)(edst + base);
        int4 r4 = *(const int4*)(rank + base);
        int4 s4 = *(const int4*)(esrc + base);
        bucket[off[d4.x] + r4.x] = s4.x;
        bucket[off[d4.y] + r4.y] = s4.y;
        bucket[off[d4.z] + r4.z] = s4.z;
        bucket[off[d4.w] + r4.w] = s4.w;
    } else {
        for (int e = base; e < E; ++e)
            bucket[off[edst[e]] + rank[e]] = esrc[e];
    }
}

__global__ __launch_bounds__(256) void k_gather(const ushort* __restrict__ Ybf,
                                                const int* __restrict__ off,
                                                const int* __restrict__ bucket,
                                                const float* __restrict__ bias,
                                                float* __restrict__ out, int N) {
    int tid = threadIdx.x;
    int w = tid >> 6, lane = tid & 63;
    int g = lane >> 3, c = lane & 7;
    int n = blockIdx.x * 4 + w;
    if (n >= N) return;
    int beg = off[n], end = off[n + 1];
    int d = end - beg;
    const uint4* Y16 = (const uint4*)Ybf;
    float acc[4][8];
#pragma unroll
    for (int ch = 0; ch < 4; ++ch)
#pragma unroll
        for (int j = 0; j < 8; ++j) acc[ch][j] = 0.f;
    int last = end - 1;
    for (int base = beg; base < end; base += 32) {
#pragma unroll
        for (int ch = 0; ch < 4; ++ch) {
            int jdx = base + ch * 8 + g;
            int s = bucket[min(jdx, last)];
            uint4 q = Y16[(long)s * 8 + c];
            if (jdx < end) {
                acc[ch][0] += __uint_as_float(q.x << 16);
                acc[ch][1] += __uint_as_float(q.x & 0xFFFF0000u);
                acc[ch][2] += __uint_as_float(q.y << 16);
                acc[ch][3] += __uint_as_float(q.y & 0xFFFF0000u);
                acc[ch][4] += __uint_as_float(q.z << 16);
                acc[ch][5] += __uint_as_float(q.z & 0xFFFF0000u);
                acc[ch][6] += __uint_as_float(q.w << 16);
                acc[ch][7] += __uint_as_float(q.w & 0xFFFF0000u);
            }
        }
    }
#pragma unroll
    for (int j = 0; j < 8; ++j)
        acc[0][j] += (acc[1][j] + acc[2][j]) + acc[3][j];
#pragma unroll
    for (int j = 0; j < 8; ++j) {
        float v = acc[0][j];
        v += __shfl_xor(v, 8);
        v += __shfl_xor(v, 16);
        v += __shfl_xor(v, 32);
        acc[0][j] = v;
    }
    float sel = acc[0][0];
#pragma unroll
    for (int j = 1; j < 8; ++j) sel = (g == j) ? acc[0][j] : sel;
    int fw = c * 8 + g;
    float hv;
    if (d > 0) {
        hv = sel / (float)d;
    } else {
        hv = __uint_as_float(((uint)Ybf[(long)n * F + fw]) << 16);
    }
    out[(long)n * F + fw] = fmaxf(hv + bias[fw], 0.0f);
}

// ---------- fallback tier C: pure atomic ----------
__global__ __launch_bounds__(256) void gcn_edge_scatter(const float* __restrict__ feature,
                                                        const int* __restrict__ esrc,
                                                        const int* __restrict__ edst,
                                                        float* __restrict__ agg,
                                                        float* __restrict__ cnt, int E) {
    int t = blockIdx.x * blockDim.x + threadIdx.x;
    int e = t >> 6, f = t & 63;
    if (e >= E) return;
    atomicAdd(&agg[(long)edst[e] * F + f], feature[(long)esrc[e] * F + f]);
    if (f == 0) atomicAdd(&cnt[edst[e]], 1.0f);
}
__global__ __launch_bounds__(256) void gcn_node_apply(const float* __restrict__ feature,
                                                      const float* __restrict__ W,
                                                      const float* __restrict__ bias,
                                                      const float* __restrict__ cnt,
                                                      float* __restrict__ inout, int N) {
    __shared__ float sWt[64 * 65];
    __shared__ float sh[4][64];
    int tid = threadIdx.x;
    for (int i = tid; i < 64 * 64; i += 256) {
        int fo = i >> 6, k = i & 63;
        sWt[k * 65 + fo] = W[i];
    }
    int w = tid >> 6, f = tid & 63;
    int n = blockIdx.x * 4 + w;
    float h = 0.0f;
    if (n < N) {
        float c = cnt[n];
        h = (c > 0.0f) ? inout[(long)n * F + f] / c : feature[(long)n * F + f];
    }
    sh[w][f] = h;
    __syncthreads();
    float acc = bias[f];
#pragma unroll
    for (int k = 0; k < 64; ++k) acc = fmaf(sh[w][k], sWt[k * 65 + f], acc);
    if (n < N) inout[(long)n * F + f] = fmaxf(acc, 0.0f);
}

extern "C" void kernel_launch(void* const* d_in, const int* in_sizes, int n_in,
                              void* d_out, int out_size, void* d_ws, size_t ws_size,
                              hipStream_t stream) {
    const float* feature = (const float*)d_in[0];
    const int*   esrc    = (const int*)d_in[1];
    const int*   edst    = (const int*)d_in[2];
    const float* W       = (const float*)d_in[3];
    const float* bias    = (const float*)d_in[4];

    int N = in_sizes[0] / F;   // 50000
    int E = in_sizes[1];       // 800000

    auto align256 = [](size_t x) { return (x + 255) & ~(size_t)255; };
    size_t sz_off    = align256((size_t)(N + 1) * sizeof(int));
    size_t sz_deg    = align256((size_t)N * sizeof(int));
    size_t sz_rank   = align256((size_t)E * sizeof(int));
    size_t sz_bucket = align256((size_t)E * sizeof(int));
    size_t sz_part   = align256(64 * sizeof(int));
    size_t sz_Y      = align256((size_t)N * F * sizeof(ushort));   // bf16
    size_t need = sz_off + sz_deg + sz_rank + sz_bucket + sz_part + sz_Y;

    int nbChunks = (N + SCAN_ELEMS - 1) / SCAN_ELEMS;  // 49, must be <= 64
    int n4  = (N + 3) / 4;
    int gE4 = (int)(((size_t)E + 1023) / 1024);

    if (ws_size >= need && nbChunks <= 64) {
        char* ws = (char*)d_ws;
        int*    off    = (int*)ws;    ws += sz_off;
        int*    deg    = (int*)ws;    ws += sz_deg;
        int*    rank   = (int*)ws;    ws += sz_rank;
        int*    bucket = (int*)ws;    ws += sz_bucket;
        int*    part   = (int*)ws;    ws += sz_part;
        ushort* Ybf    = (ushort*)ws;
        float*  out    = (float*)d_out;

        // dispatch 1: GEMM (also zeroes deg)
        k_gemm<<<(N + 31) / 32, 256, 0, stream>>>(feature, W, Ybf, N, deg, n4);

        // dispatch 2: cooperative fused sort+gather
        bool done = false;
        int dev = 0;
        hipGetDevice(&dev);
        int coop = 0, nCU = 0, perCU = 0;
        hipDeviceGetAttribute(&coop, hipDeviceAttributeCooperativeLaunch, dev);
        hipDeviceGetAttribute(&nCU, hipDeviceAttributeMultiprocessorCount, dev);
        hipOccupancyMaxActiveBlocksPerMultiprocessor(&perCU, k_fused, 256, 0);
        if (coop && nCU > 0 && perCU > 0) {
            int NB = perCU * nCU;
            if (NB > 2048) NB = 2048;
            if (NB >= nbChunks) {
                void* args[] = { (void*)&esrc, (void*)&edst, (void*)&deg,
                                 (void*)&rank, (void*)&part, (void*)&off,
                                 (void*)&bucket, (void*)&Ybf, (void*)&bias,
                                 (void*)&out, (void*)&N, (void*)&E,
                                 (void*)&nbChunks };
                hipError_t ce = hipLaunchCooperativeKernel(
                    (void*)k_fused, dim3(NB), dim3(256), args, 0, stream);
                done = (ce == hipSuccess);
            }
        }
        if (!done) {
            // proven round-11 multi-kernel fallback (deg already zeroed by k_gemm)
            k_deg<<<gE4, 256, 0, stream>>>(edst, deg, rank, E);
            k_part<<<nbChunks, SCAN_BLK, 0, stream>>>(deg, part, N);
            k_final<<<nbChunks, SCAN_BLK, 0, stream>>>(deg, part, off, N, E, nbChunks);
            k_bucket<<<gE4, 256, 0, stream>>>(esrc, edst, off, rank, bucket, E);
            k_gather<<<(N + 3) / 4, 256, 0, stream>>>(Ybf, off, bucket, bias, out, N);
        }
    } else {
        float* agg = (float*)d_out;
        float* cnt = (float*)d_ws;
        hipMemsetAsync(agg, 0, (size_t)N * F * sizeof(float), stream);
        hipMemsetAsync(cnt, 0, (size_t)N * sizeof(float), stream);
        long total = (long)E * F;
        gcn_edge_scatter<<<(int)((total + 255) / 256), 256, 0, stream>>>(
            feature, esrc, edst, agg, cnt, E);
        gcn_node_apply<<<(N + 3) / 4, 256, 0, stream>>>(feature, W, bias, cnt, agg, N);
    }
}

// Round 13
// 91.518 us; speedup vs baseline: 5.7452x; 5.7452x over previous
//
#include <hip/hip_runtime.h>

// GCN layer: out = relu( G(feature) @ W^T + b ), G = mean over in-edges (or
// identity for isolated nodes).  N=50000, F=64, E=800000.
//
// GEMM commutes with the (linear) aggregation: G(feat)@W^T == G(feat@W^T).
// Round-13: scan-free bucketing. rank = atomicAdd(&deg[dst],1) IS the bucket
// slot (bucket[dst*CAP + rank]), so histogram+scatter fuse into one kernel and
// k_part/k_final/k_bucket disappear. CAP=48 >> max Poisson(16) degree; an
// overflow list keeps any-input correctness (always empty here).
// 3 dispatches: k_gemm(+zero) -> k_scatter -> k_gather.
// (Round-12 lesson: cooperative grid.sync costs ~200us each on MI355X's
// 8 XCDs - 850us kernel at 1.6% VALUBusy. Never again.)

#define F 64
#define CAP 48          // bucket slots per node
#define OVF_MAX 32768   // overflow capacity (never used for this input)
#define SCAN_BLK 256
#define SCAN_ELEMS 1024

typedef unsigned int uint;
typedef unsigned short ushort;

__device__ __forceinline__ ushort f2bf(float x) {
    uint u = __float_as_uint(x);
    u += 0x7FFFu + ((u >> 16) & 1u);   // round-to-nearest-even
    return (ushort)(u >> 16);
}

// ---------- D1: Ybf = bf16( feature @ W^T ), plus deg/ovf zeroing ----------
__global__ __launch_bounds__(256) void k_gemm(const float* __restrict__ feature,
                                              const float* __restrict__ W,
                                              ushort* __restrict__ Ybf, int N,
                                              int* __restrict__ deg, int n4,
                                              int* __restrict__ ovf) {
    {
        int gt = blockIdx.x * 256 + threadIdx.x;
        if (gt == 0) ovf[0] = 0;
        for (int i = gt; i < n4; i += gridDim.x * 256)
            ((int4*)deg)[i] = make_int4(0, 0, 0, 0);
    }
    __shared__ float sWt[64 * 76];
    __shared__ float shh[32 * 72];
    int tid = threadIdx.x;
    for (int i = tid; i < 4096; i += 256) {
        int fo = i >> 6, k = i & 63;
        sWt[k * 76 + fo] = W[i];
    }
    int n0blk = blockIdx.x * 32;
    for (int i = tid; i < 512; i += 256) {        // 32 rows x 16 float4
        int r = i >> 4, c4 = i & 15;
        int n = n0blk + r;
        float4 v = make_float4(0.f, 0.f, 0.f, 0.f);
        if (n < N) v = ((const float4*)feature)[(long)n * 16 + c4];
        *(float4*)&shh[r * 72 + c4 * 4] = v;
    }
    __syncthreads();
    int npair = tid >> 4, foq = tid & 15;
    int r0 = npair * 2, r1 = r0 + 1;
    float a0=0,a1=0,a2=0,a3=0,b0=0,b1=0,b2=0,b3=0;
#pragma unroll 8
    for (int k = 0; k < 64; ++k) {
        float hA = shh[r0 * 72 + k];
        float hB = shh[r1 * 72 + k];
        float4 wv = *(const float4*)&sWt[k * 76 + foq * 4];
        a0 = fmaf(hA, wv.x, a0); a1 = fmaf(hA, wv.y, a1);
        a2 = fmaf(hA, wv.z, a2); a3 = fmaf(hA, wv.w, a3);
        b0 = fmaf(hB, wv.x, b0); b1 = fmaf(hB, wv.y, b1);
        b2 = fmaf(hB, wv.z, b2); b3 = fmaf(hB, wv.w, b3);
    }
    int nA = n0blk + r0, nB = n0blk + r1;
    if (nA < N) ((ushort4*)Ybf)[(long)nA * 16 + foq] =
        make_ushort4(f2bf(a0), f2bf(a1), f2bf(a2), f2bf(a3));
    if (nB < N) ((ushort4*)Ybf)[(long)nB * 16 + foq] =
        make_ushort4(f2bf(b0), f2bf(b1), f2bf(b2), f2bf(b3));
}

// ---------- D2: fused histogram + direct bucket scatter (scan-free) --------
__global__ __launch_bounds__(256) void k_scatter(const int* __restrict__ esrc,
                                                 const int* __restrict__ edst,
                                                 int* __restrict__ deg,
                                                 int* __restrict__ bucket,
                                                 int* __restrict__ ovf, int E) {
    int base = (blockIdx.x * 256 + threadIdx.x) * 4;
    if (base + 3 < E) {
        int4 d4 = *(const int4*)(edst + base);
        int4 s4 = *(const int4*)(esrc + base);
        int r0 = atomicAdd(&deg[d4.x], 1);
        int r1 = atomicAdd(&deg[d4.y], 1);
        int r2 = atomicAdd(&deg[d4.z], 1);
        int r3 = atomicAdd(&deg[d4.w], 1);
        if (r0 < CAP) bucket[d4.x * CAP + r0] = s4.x;
        else { int o = atomicAdd(&ovf[0], 1); if (o < OVF_MAX) { ovf[2 + 2*o] = d4.x; ovf[3 + 2*o] = s4.x; } }
        if (r1 < CAP) bucket[d4.y * CAP + r1] = s4.y;
        else { int o = atomicAdd(&ovf[0], 1); if (o < OVF_MAX) { ovf[2 + 2*o] = d4.y; ovf[3 + 2*o] = s4.y; } }
        if (r2 < CAP) bucket[d4.z * CAP + r2] = s4.z;
        else { int o = atomicAdd(&ovf[0], 1); if (o < OVF_MAX) { ovf[2 + 2*o] = d4.z; ovf[3 + 2*o] = s4.z; } }
        if (r3 < CAP) bucket[d4.w * CAP + r3] = s4.w;
        else { int o = atomicAdd(&ovf[0], 1); if (o < OVF_MAX) { ovf[2 + 2*o] = d4.w; ovf[3 + 2*o] = s4.w; } }
    } else {
        for (int e = base; e < E; ++e) {
            int d = edst[e], s = esrc[e];
            int r = atomicAdd(&deg[d], 1);
            if (r < CAP) bucket[d * CAP + r] = s;
            else { int o = atomicAdd(&ovf[0], 1); if (o < OVF_MAX) { ovf[2 + 2*o] = d; ovf[3 + 2*o] = s; } }
        }
    }
}

// ---------- D3: gather-mean over bf16 Y + bias + relu ----------
// lane = (g<<3)|c : g = edge slot 0..7, c = ushort8 column 0..7.
__global__ __launch_bounds__(256) void k_gather(const ushort* __restrict__ Ybf,
                                                const int* __restrict__ deg,
                                                const int* __restrict__ bucket,
                                                const int* __restrict__ ovf,
                                                const float* __restrict__ bias,
                                                float* __restrict__ out, int N) {
    int tid = threadIdx.x;
    int w = tid >> 6, lane = tid & 63;
    int g = lane >> 3, c = lane & 7;
    int n = blockIdx.x * 4 + w;
    if (n >= N) return;
    int d = deg[n];
    int m = min(d, CAP);
    int boff = n * CAP;
    const uint4* Y16 = (const uint4*)Ybf;
    float acc[4][8];
#pragma unroll
    for (int ch = 0; ch < 4; ++ch)
#pragma unroll
        for (int j = 0; j < 8; ++j) acc[ch][j] = 0.f;
    int last = m - 1;
    for (int base = 0; base < m; base += 32) {
#pragma unroll
        for (int ch = 0; ch < 4; ++ch) {
            int jdx = base + ch * 8 + g;
            int s = bucket[boff + min(jdx, last)];
            uint4 q = Y16[(long)s * 8 + c];
            if (jdx < m) {
                acc[ch][0] += __uint_as_float(q.x << 16);
                acc[ch][1] += __uint_as_float(q.x & 0xFFFF0000u);
                acc[ch][2] += __uint_as_float(q.y << 16);
                acc[ch][3] += __uint_as_float(q.y & 0xFFFF0000u);
                acc[ch][4] += __uint_as_float(q.z << 16);
                acc[ch][5] += __uint_as_float(q.z & 0xFFFF0000u);
                acc[ch][6] += __uint_as_float(q.w << 16);
                acc[ch][7] += __uint_as_float(q.w & 0xFFFF0000u);
            }
        }
    }
    // overflow tail (empty for this input; correctness for any input).
    if (d > CAP) {
        int no = ovf[0]; if (no > OVF_MAX) no = OVF_MAX;
        if (g == 0) {                       // add once (g==0 group: 8 lanes x 8 feats)
            for (int i = 0; i < no; ++i) {
                if (ovf[2 + 2*i] == n) {
                    int s = ovf[3 + 2*i];
                    uint4 q = Y16[(long)s * 8 + c];
                    acc[0][0] += __uint_as_float(q.x << 16);
                    acc[0][1] += __uint_as_float(q.x & 0xFFFF0000u);
                    acc[0][2] += __uint_as_float(q.y << 16);
                    acc[0][3] += __uint_as_float(q.y & 0xFFFF0000u);
                    acc[0][4] += __uint_as_float(q.z << 16);
                    acc[0][5] += __uint_as_float(q.z & 0xFFFF0000u);
                    acc[0][6] += __uint_as_float(q.w << 16);
                    acc[0][7] += __uint_as_float(q.w & 0xFFFF0000u);
                }
            }
        }
    }
#pragma unroll
    for (int j = 0; j < 8; ++j)
        acc[0][j] += (acc[1][j] + acc[2][j]) + acc[3][j];
#pragma unroll
    for (int j = 0; j < 8; ++j) {
        float v = acc[0][j];
        v += __shfl_xor(v, 8);
        v += __shfl_xor(v, 16);
        v += __shfl_xor(v, 32);
        acc[0][j] = v;
    }
    float sel = acc[0][0];
#pragma unroll
    for (int j = 1; j < 8; ++j) sel = (g == j) ? acc[0][j] : sel;
    int fw = c * 8 + g;
    float hv;
    if (d > 0) {
        hv = sel / (float)d;
    } else {
        hv = __uint_as_float(((uint)Ybf[(long)n * F + fw]) << 16);
    }
    out[(long)n * F + fw] = fmaxf(hv + bias[fw], 0.0f);
}

// ---------- fallback tier C: pure atomic (tiny ws) ----------
__global__ __launch_bounds__(256) void gcn_edge_scatter(const float* __restrict__ feature,
                                                        const int* __restrict__ esrc,
                                                        const int* __restrict__ edst,
                                                        float* __restrict__ agg,
                                                        float* __restrict__ cnt, int E) {
    int t = blockIdx.x * blockDim.x + threadIdx.x;
    int e = t >> 6, f = t & 63;
    if (e >= E) return;
    atomicAdd(&agg[(long)edst[e] * F + f], feature[(long)esrc[e] * F + f]);
    if (f == 0) atomicAdd(&cnt[edst[e]], 1.0f);
}
__global__ __launch_bounds__(256) void gcn_node_apply(const float* __restrict__ feature,
                                                      const float* __restrict__ W,
                                                      const float* __restrict__ bias,
                                                      const float* __restrict__ cnt,
                                                      float* __restrict__ inout, int N) {
    __shared__ float sWt[64 * 65];
    __shared__ float sh[4][64];
    int tid = threadIdx.x;
    for (int i = tid; i < 64 * 64; i += 256) {
        int fo = i >> 6, k = i & 63;
        sWt[k * 65 + fo] = W[i];
    }
    int w = tid >> 6, f = tid & 63;
    int n = blockIdx.x * 4 + w;
    float h = 0.0f;
    if (n < N) {
        float c = cnt[n];
        h = (c > 0.0f) ? inout[(long)n * F + f] / c : feature[(long)n * F + f];
    }
    sh[w][f] = h;
    __syncthreads();
    float acc = bias[f];
#pragma unroll
    for (int k = 0; k < 64; ++k) acc = fmaf(sh[w][k], sWt[k * 65 + f], acc);
    if (n < N) inout[(long)n * F + f] = fmaxf(acc, 0.0f);
}

extern "C" void kernel_launch(void* const* d_in, const int* in_sizes, int n_in,
                              void* d_out, int out_size, void* d_ws, size_t ws_size,
                              hipStream_t stream) {
    const float* feature = (const float*)d_in[0];
    const int*   esrc    = (const int*)d_in[1];
    const int*   edst    = (const int*)d_in[2];
    const float* W       = (const float*)d_in[3];
    const float* bias    = (const float*)d_in[4];

    int N = in_sizes[0] / F;   // 50000
    int E = in_sizes[1];       // 800000

    auto align256 = [](size_t x) { return (x + 255) & ~(size_t)255; };
    size_t sz_deg    = align256((size_t)N * sizeof(int));
    size_t sz_ovf    = align256((2 + 2 * (size_t)OVF_MAX) * sizeof(int));
    size_t sz_bucket = align256((size_t)N * CAP * sizeof(int));
    size_t sz_Y      = align256((size_t)N * F * sizeof(ushort));   // bf16
    size_t need = sz_deg + sz_ovf + sz_bucket + sz_Y;

    int n4  = (N + 3) / 4;
    int gE4 = (int)(((size_t)E + 1023) / 1024);       // 4 edges/thread

    if (ws_size >= need) {
        char* ws = (char*)d_ws;
        int*    deg    = (int*)ws;    ws += sz_deg;
        int*    ovf    = (int*)ws;    ws += sz_ovf;
        int*    bucket = (int*)ws;    ws += sz_bucket;
        ushort* Ybf    = (ushort*)ws;
        float*  out    = (float*)d_out;

        k_gemm<<<(N + 31) / 32, 256, 0, stream>>>(feature, W, Ybf, N, deg, n4, ovf);
        k_scatter<<<gE4, 256, 0, stream>>>(esrc, edst, deg, bucket, ovf, E);
        k_gather<<<(N + 3) / 4, 256, 0, stream>>>(Ybf, deg, bucket, ovf, bias, out, N);
    } else {
        float* agg = (float*)d_out;
        float* cnt = (float*)d_ws;
        hipMemsetAsync(agg, 0, (size_t)N * F * sizeof(float), stream);
        hipMemsetAsync(cnt, 0, (size_t)N * sizeof(float), stream);
        long total = (long)E * F;
        gcn_edge_scatter<<<(int)((total + 255) / 256), 256, 0, stream>>>(
            feature, esrc, edst, agg, cnt, E);
        gcn_node_apply<<<(N + 3) / 4, 256, 0, stream>>>(feature, W, bias, cnt, agg, N);
    }
}